// Round 2
// baseline (1432.730 us; speedup 1.0000x reference)
//
#include <hip/hip_runtime.h>
#include <hip/hip_bf16.h>

#define NN 50000
#define NE 500000
#define F 128
#define K_IN 128
#define ED 64
#define C 2
#define NEG 0.2f

// ---------------- projection: x_base = x @ W_l^T ----------------
__global__ __launch_bounds__(256) void proj_kernel(const float* __restrict__ x,
                                                   const float* __restrict__ W_l,
                                                   float* __restrict__ xb,
                                                   int nodes_per_block) {
    __shared__ float Wt[K_IN][F]; // Wt[k][f] = W_l[f][k], 64KB
    for (int i = threadIdx.x; i < F * K_IN; i += 256) {
        int f = i & (F - 1), k = i >> 7;
        Wt[k][f] = W_l[f * K_IN + k];
    }
    __syncthreads();
    int node0 = blockIdx.x * nodes_per_block;
    int node_end = min(node0 + nodes_per_block, NN);
    int half = threadIdx.x >> 7;
    int f = threadIdx.x & (F - 1);
    for (int n = node0 + half; n < node_end; n += 2) {
        const float* xr = x + (size_t)n * K_IN;
        float acc = 0.f;
#pragma unroll 8
        for (int k = 0; k < K_IN; ++k)
            acc = fmaf(xr[k], Wt[k][f], acc);
        xb[(size_t)n * F + f] = acc;
    }
}

// ---------------- CSR build ----------------
__global__ void hist_kernel(const int* __restrict__ ei, int* __restrict__ counts) {
    int e = blockIdx.x * blockDim.x + threadIdx.x;
    if (e < NE) atomicAdd(&counts[ei[NE + e]], 1);
}

__global__ __launch_bounds__(1024) void scan_kernel(const int* __restrict__ counts,
                                                    int* __restrict__ offs,
                                                    int* __restrict__ cursor) {
    __shared__ int tmp[1024];
    __shared__ int carry_s;
    if (threadIdx.x == 0) carry_s = 0;
    __syncthreads();
    for (int base = 0; base < NN; base += 1024) {
        int i = base + threadIdx.x;
        int v = (i < NN) ? counts[i] : 0;
        tmp[threadIdx.x] = v;
        __syncthreads();
        for (int off = 1; off < 1024; off <<= 1) {
            int add = (threadIdx.x >= off) ? tmp[threadIdx.x - off] : 0;
            __syncthreads();
            tmp[threadIdx.x] += add;
            __syncthreads();
        }
        int excl = tmp[threadIdx.x] - v;
        int carry = carry_s;
        if (i < NN) { offs[i] = carry + excl; cursor[i] = carry + excl; }
        __syncthreads();
        if (threadIdx.x == 0) carry_s = carry + tmp[1023];
        __syncthreads();
    }
    if (threadIdx.x == 0) offs[NN] = carry_s;
}

__global__ void scatter_kernel(const int* __restrict__ ei, int* __restrict__ cursor,
                               int* __restrict__ perm) {
    int e = blockIdx.x * blockDim.x + threadIdx.x;
    if (e < NE) {
        int p = atomicAdd(&cursor[ei[NE + e]], 1);
        perm[p] = e;
    }
}

// ---------------- per-edge logits (no atomics) ----------------
__global__ __launch_bounds__(256) void edge_logits_kernel(
    const int* __restrict__ ei, const float* __restrict__ ea,
    const float* __restrict__ xb, const float* __restrict__ W_e,
    const float* __restrict__ cb, const float* __restrict__ att,
    const float* __restrict__ att_sc, const float* __restrict__ ebias,
    float* __restrict__ logits) {
    __shared__ float WeT[ED][F];
    __shared__ float att_s[F];
    __shared__ float cb_s[C][F];
    __shared__ float eb_s[C][F];
    for (int i = threadIdx.x; i < ED * F; i += 256) {
        int f = i & (F - 1), k = i >> 7;
        WeT[k][f] = W_e[f * ED + k];
    }
    for (int i = threadIdx.x; i < F; i += 256) att_s[i] = att[i];
    for (int i = threadIdx.x; i < C * F; i += 256) {
        int c = i >> 7, f = i & (F - 1);
        cb_s[c][f] = cb[c * F + f];
        eb_s[c][f] = ebias[f * C + c];
    }
    float as0 = att_sc[0], as1 = att_sc[1];
    __syncthreads();

    int lane = threadIdx.x & 63;
    int wid = blockIdx.x * 4 + (threadIdx.x >> 6);
    int stride = gridDim.x * 4;
    for (int e = wid; e < NE; e += stride) {
        int src = ei[e];
        int tgt = ei[NE + e];
        float eav = ea[(size_t)e * ED + lane];
        float emb0 = 0.f, emb1 = 0.f;
#pragma unroll
        for (int k = 0; k < ED; ++k) {
            float a = __shfl(eav, k, 64);
            emb0 = fmaf(a, WeT[k][lane], emb0);
            emb1 = fmaf(a, WeT[k][lane + 64], emb1);
        }
        float xj0 = xb[(size_t)src * F + lane];
        float xj1 = xb[(size_t)src * F + lane + 64];
        float xi0 = xb[(size_t)tgt * F + lane];
        float xi1 = xb[(size_t)tgt * F + lane + 64];
        float p0, p1;
        {
            float t0 = xi0 + cb_s[0][lane] + xj0 + emb0 + eb_s[0][lane];
            float t1 = xi1 + cb_s[0][lane + 64] + xj1 + emb1 + eb_s[0][lane + 64];
            t0 = t0 > 0.f ? t0 : NEG * t0;
            t1 = t1 > 0.f ? t1 : NEG * t1;
            p0 = fmaf(t0, att_s[lane], t1 * att_s[lane + 64]);
        }
        {
            float t0 = xi0 + cb_s[1][lane] + xj0 + emb0 + eb_s[1][lane];
            float t1 = xi1 + cb_s[1][lane + 64] + xj1 + emb1 + eb_s[1][lane + 64];
            t0 = t0 > 0.f ? t0 : NEG * t0;
            t1 = t1 > 0.f ? t1 : NEG * t1;
            p1 = fmaf(t0, att_s[lane], t1 * att_s[lane + 64]);
        }
#pragma unroll
        for (int off = 32; off > 0; off >>= 1) {
            p0 += __shfl_xor(p0, off, 64);
            p1 += __shfl_xor(p1, off, 64);
        }
        if (lane == 0) {
            logits[2 * (size_t)e] = p0 * as0;
            logits[2 * (size_t)e + 1] = p1 * as1;
        }
    }
}

// ---------------- CSR aggregation: local softmax + register row accum ----------------
__global__ __launch_bounds__(256) void agg_csr_kernel(
    const int* __restrict__ ei, const int* __restrict__ offs,
    const int* __restrict__ perm, const float* __restrict__ ea,
    const float* __restrict__ xb, const float* __restrict__ W_e,
    const float* __restrict__ ebias, const float* __restrict__ logits,
    float* __restrict__ out, float* __restrict__ alpha_out) {
    __shared__ float WeT[ED][F];
    __shared__ float eb_s[C][F];
    for (int i = threadIdx.x; i < ED * F; i += 256) {
        int f = i & (F - 1), k = i >> 7;
        WeT[k][f] = W_e[f * ED + k];
    }
    for (int i = threadIdx.x; i < C * F; i += 256) {
        int c = i >> 7, f = i & (F - 1);
        eb_s[c][f] = ebias[f * C + c];
    }
    __syncthreads();

    int lane = threadIdx.x & 63;
    int node = blockIdx.x * 4 + (threadIdx.x >> 6);
    if (node >= NN) return;
    int beg = offs[node], end = offs[node + 1];
    float* orow = out + (size_t)node * (C * F);
    if (beg == end) {
        orow[lane] = 0.f; orow[64 + lane] = 0.f;
        orow[128 + lane] = 0.f; orow[192 + lane] = 0.f;
        return;
    }
    // local segment max
    float m0 = -3.402823466e38f, m1 = -3.402823466e38f;
    for (int j = beg + lane; j < end; j += 64) {
        int e = perm[j];
        m0 = fmaxf(m0, logits[2 * (size_t)e]);
        m1 = fmaxf(m1, logits[2 * (size_t)e + 1]);
    }
#pragma unroll
    for (int off = 32; off > 0; off >>= 1) {
        m0 = fmaxf(m0, __shfl_xor(m0, off, 64));
        m1 = fmaxf(m1, __shfl_xor(m1, off, 64));
    }
    // local segment sum
    float s0 = 0.f, s1 = 0.f;
    for (int j = beg + lane; j < end; j += 64) {
        int e = perm[j];
        s0 += expf(logits[2 * (size_t)e] - m0);
        s1 += expf(logits[2 * (size_t)e + 1] - m1);
    }
#pragma unroll
    for (int off = 32; off > 0; off >>= 1) {
        s0 += __shfl_xor(s0, off, 64);
        s1 += __shfl_xor(s1, off, 64);
    }
    float inv0 = 1.f / (s0 + 1e-16f), inv1 = 1.f / (s1 + 1e-16f);
    // alpha output
    for (int j = beg + lane; j < end; j += 64) {
        int e = perm[j];
        alpha_out[2 * (size_t)e]     = expf(logits[2 * (size_t)e] - m0) * inv0;
        alpha_out[2 * (size_t)e + 1] = expf(logits[2 * (size_t)e + 1] - m1) * inv1;
    }
    // aggregate messages (serial over this node's edges, lanes cover F)
    float acc00 = 0.f, acc10 = 0.f, acc01 = 0.f, acc11 = 0.f;
    for (int j = beg; j < end; ++j) {
        int e = __builtin_amdgcn_readfirstlane(perm[j]);
        float a0 = expf(logits[2 * (size_t)e] - m0) * inv0;
        float a1 = expf(logits[2 * (size_t)e + 1] - m1) * inv1;
        int src = ei[e];
        float eav = ea[(size_t)e * ED + lane];
        float emb0 = 0.f, emb1 = 0.f;
#pragma unroll
        for (int k = 0; k < ED; ++k) {
            float a = __shfl(eav, k, 64);
            emb0 = fmaf(a, WeT[k][lane], emb0);
            emb1 = fmaf(a, WeT[k][lane + 64], emb1);
        }
        float b0 = xb[(size_t)src * F + lane] + emb0;
        float b1 = xb[(size_t)src * F + lane + 64] + emb1;
        acc00 = fmaf(b0, a0, acc00);
        acc01 = fmaf(b0, a1, acc01);
        acc10 = fmaf(b1, a0, acc10);
        acc11 = fmaf(b1, a1, acc11);
    }
    // epilogue: add factored edge-bias * sum(alpha)
    float sa0 = s0 * inv0, sa1 = s1 * inv1;
    orow[lane]       = fmaf(eb_s[0][lane],      sa0, acc00);
    orow[64 + lane]  = fmaf(eb_s[0][lane + 64], sa0, acc10);
    orow[128 + lane] = fmaf(eb_s[1][lane],      sa1, acc01);
    orow[192 + lane] = fmaf(eb_s[1][lane + 64], sa1, acc11);
}

extern "C" void kernel_launch(void* const* d_in, const int* in_sizes, int n_in,
                              void* d_out, int out_size, void* d_ws, size_t ws_size,
                              hipStream_t stream) {
    const float* x      = (const float*)d_in[0];
    const int*   ei     = (const int*)d_in[1];
    const float* ea     = (const float*)d_in[2];
    const float* W_l    = (const float*)d_in[3];
    const float* cb     = (const float*)d_in[4];
    const float* att    = (const float*)d_in[5];
    const float* att_sc = (const float*)d_in[6];
    const float* W_e    = (const float*)d_in[7];
    const float* ebias  = (const float*)d_in[8];

    float* out = (float*)d_out;
    float* alpha_out = out + (size_t)NN * C * F;

    float* ws = (float*)d_ws;
    float* xb     = ws;                    // 6.4M floats
    float* logits = ws + 6400000;          // 1.0M floats
    int* ibase  = (int*)(ws + 7400000);
    int* counts = ibase;                   // NN
    int* offs   = ibase + NN;              // NN+1
    int* cursor = ibase + 2 * NN + 1;      // NN
    int* perm   = ibase + 3 * NN + 1;      // NE

    hipMemsetAsync(counts, 0, NN * sizeof(int), stream);

    proj_kernel<<<1000, 256, 0, stream>>>(x, W_l, xb, 50);

    hist_kernel<<<(NE + 255) / 256, 256, 0, stream>>>(ei, counts);
    scan_kernel<<<1, 1024, 0, stream>>>(counts, offs, cursor);
    scatter_kernel<<<(NE + 255) / 256, 256, 0, stream>>>(ei, cursor, perm);

    edge_logits_kernel<<<1024, 256, 0, stream>>>(ei, ea, xb, W_e, cb, att,
                                                 att_sc, ebias, logits);

    agg_csr_kernel<<<(NN + 3) / 4, 256, 0, stream>>>(ei, offs, perm, ea, xb, W_e,
                                                     ebias, logits, out, alpha_out);
}

// Round 3
// 654.589 us; speedup vs baseline: 2.1887x; 2.1887x over previous
//
#include <hip/hip_runtime.h>
#include <hip/hip_bf16.h>

#define NN 50000
#define NE 500000
#define F 128
#define K_IN 128
#define ED 64
#define C 2
#define NEG 0.2f

typedef __attribute__((ext_vector_type(8))) short short8;
typedef __attribute__((ext_vector_type(4))) float f32x4;

__device__ __forceinline__ short bf16r(float f) {
    unsigned u = __float_as_uint(f);
    unsigned r = (u + 0x7fffu + ((u >> 16) & 1u)) >> 16;
    return (short)r;
}

// load 8 consecutive fp32 -> bf16x8 fragment
__device__ __forceinline__ short8 ldfrag(const float* base) {
    const float4* p = reinterpret_cast<const float4*>(base);
    float4 v0 = p[0], v1 = p[1];
    short8 r;
    r[0] = bf16r(v0.x); r[1] = bf16r(v0.y); r[2] = bf16r(v0.z); r[3] = bf16r(v0.w);
    r[4] = bf16r(v1.x); r[5] = bf16r(v1.y); r[6] = bf16r(v1.z); r[7] = bf16r(v1.w);
    return r;
}

// ---------------- projection via MFMA: xb = x @ W_l^T ----------------
__global__ __launch_bounds__(256) void proj_mfma(const float* __restrict__ x,
                                                 const float* __restrict__ W_l,
                                                 float* __restrict__ xb) {
    int lane = threadIdx.x & 63, wid = threadIdx.x >> 6;
    int grp = lane >> 4, col = lane & 15;
    int tile = blockIdx.x * 4 + wid;
    if (tile >= NN / 16) return;   // 3125 tiles exactly
    int n0 = tile * 16;

    f32x4 acc[8];
#pragma unroll
    for (int t = 0; t < 8; ++t) acc[t] = (f32x4){0.f, 0.f, 0.f, 0.f};

    const float* arow = x + (size_t)(n0 + col) * K_IN + grp * 8;
#pragma unroll
    for (int kt = 0; kt < 4; ++kt) {
        short8 a = ldfrag(arow + kt * 32);
#pragma unroll
        for (int t = 0; t < 8; ++t) {
            short8 b = ldfrag(W_l + (size_t)(t * 16 + col) * K_IN + kt * 32 + grp * 8);
            acc[t] = __builtin_amdgcn_mfma_f32_16x16x32_bf16(a, b, acc[t], 0, 0, 0);
        }
    }
#pragma unroll
    for (int j = 0; j < 4; ++j) {
        float* orow = xb + (size_t)(n0 + grp * 4 + j) * F + col;
#pragma unroll
        for (int t = 0; t < 8; ++t) orow[t * 16] = acc[t][j];
    }
}

// ---------------- CSR build ----------------
__global__ void hist_kernel(const int* __restrict__ ei, int* __restrict__ counts) {
    int e = blockIdx.x * blockDim.x + threadIdx.x;
    if (e < NE) atomicAdd(&counts[ei[NE + e]], 1);
}

__global__ __launch_bounds__(1024) void scan_kernel(const int* __restrict__ counts,
                                                    int* __restrict__ offs,
                                                    int* __restrict__ cursor) {
    __shared__ int tmp[1024];
    __shared__ int carry_s;
    if (threadIdx.x == 0) carry_s = 0;
    __syncthreads();
    for (int base = 0; base < NN; base += 1024) {
        int i = base + threadIdx.x;
        int v = (i < NN) ? counts[i] : 0;
        tmp[threadIdx.x] = v;
        __syncthreads();
        for (int off = 1; off < 1024; off <<= 1) {
            int add = (threadIdx.x >= off) ? tmp[threadIdx.x - off] : 0;
            __syncthreads();
            tmp[threadIdx.x] += add;
            __syncthreads();
        }
        int excl = tmp[threadIdx.x] - v;
        int carry = carry_s;
        if (i < NN) { offs[i] = carry + excl; cursor[i] = carry + excl; }
        __syncthreads();
        if (threadIdx.x == 0) carry_s = carry + tmp[1023];
        __syncthreads();
    }
    if (threadIdx.x == 0) offs[NN] = carry_s;
}

__global__ void scatter_kernel(const int* __restrict__ ei, int* __restrict__ cursor,
                               int* __restrict__ perm) {
    int e = blockIdx.x * blockDim.x + threadIdx.x;
    if (e < NE) {
        int p = atomicAdd(&cursor[ei[NE + e]], 1);
        perm[p] = e;
    }
}

// ---------------- edge logits via MFMA emb ----------------
// wave handles 16 edges: emb[16][128] = ea_tile(bf16) @ W_e^T(bf16) via 16 MFMAs,
// logits computed directly in D-fragment layout.
__global__ __launch_bounds__(256) void edge_logits_mfma(
    const int* __restrict__ ei, const float* __restrict__ ea,
    const float* __restrict__ xb, const float* __restrict__ W_e,
    const float* __restrict__ cb, const float* __restrict__ att,
    const float* __restrict__ att_sc, const float* __restrict__ ebias,
    float* __restrict__ logits) {
    int lane = threadIdx.x & 63, wid = threadIdx.x >> 6;
    int grp = lane >> 4, col = lane & 15;

    // B fragments: 8 n-tiles x 2 k-tiles, held in registers for all tiles
    short8 B[8][2];
#pragma unroll
    for (int t = 0; t < 8; ++t)
#pragma unroll
        for (int kt = 0; kt < 2; ++kt)
            B[t][kt] = ldfrag(W_e + (size_t)(t * 16 + col) * ED + kt * 32 + grp * 8);

    // per-lane attention vector and combined biases at f = t*16+col
    float attv[8], cbe0[8], cbe1[8];
#pragma unroll
    for (int t = 0; t < 8; ++t) {
        int f = t * 16 + col;
        attv[t] = att[f];
        cbe0[t] = cb[f] + ebias[f * 2];
        cbe1[t] = cb[F + f] + ebias[f * 2 + 1];
    }
    float as0 = att_sc[0], as1 = att_sc[1];

    for (int tile = blockIdx.x * 4 + wid; tile < NE / 16; tile += gridDim.x * 4) {
        int e0 = tile * 16;
        const float* arow = ea + (size_t)(e0 + col) * ED + grp * 8;
        short8 a0 = ldfrag(arow);
        short8 a1 = ldfrag(arow + 32);
        f32x4 acc[8];
#pragma unroll
        for (int t = 0; t < 8; ++t) acc[t] = (f32x4){0.f, 0.f, 0.f, 0.f};
#pragma unroll
        for (int t = 0; t < 8; ++t) {
            acc[t] = __builtin_amdgcn_mfma_f32_16x16x32_bf16(a0, B[t][0], acc[t], 0, 0, 0);
            acc[t] = __builtin_amdgcn_mfma_f32_16x16x32_bf16(a1, B[t][1], acc[t], 0, 0, 0);
        }
#pragma unroll
        for (int j = 0; j < 4; ++j) {
            int e = e0 + grp * 4 + j;
            int src = ei[e], tgt = ei[NE + e];
            const float* xbs = xb + (size_t)src * F + col;
            const float* xbt = xb + (size_t)tgt * F + col;
            float q0 = 0.f, q1 = 0.f;
#pragma unroll
            for (int t = 0; t < 8; ++t) {
                float s = xbs[t * 16] + xbt[t * 16] + acc[t][j];
                float u0 = s + cbe0[t]; u0 = fmaxf(u0, NEG * u0);
                float u1 = s + cbe1[t]; u1 = fmaxf(u1, NEG * u1);
                q0 = fmaf(u0, attv[t], q0);
                q1 = fmaf(u1, attv[t], q1);
            }
#pragma unroll
            for (int off = 8; off; off >>= 1) {
                q0 += __shfl_xor(q0, off, 16);
                q1 += __shfl_xor(q1, off, 16);
            }
            if (col == 0) {
                float2 o; o.x = q0 * as0; o.y = q1 * as1;
                *reinterpret_cast<float2*>(logits + 2 * (size_t)e) = o;
            }
        }
    }
}

// ---------------- factored CSR aggregation ----------------
// out[n] = g + W_e·h + eb*sum(alpha), h = sum(alpha*ea), g = sum(alpha*xb[src])
__global__ __launch_bounds__(256) void agg_factored(
    const int* __restrict__ ei, const int* __restrict__ offs,
    const int* __restrict__ perm, const float* __restrict__ ea,
    const float* __restrict__ xb, const float* __restrict__ W_e,
    const float* __restrict__ ebias, const float* __restrict__ logits,
    float* __restrict__ out, float* __restrict__ alpha_out) {
    __shared__ float WeT[ED][F]; // WeT[k][f] = W_e[f][k]
    __shared__ float ebs[C * F]; // ebs[c*F+f]
    for (int i = threadIdx.x; i < ED * F; i += 256) {
        int f = i & (F - 1), k = i >> 7;
        WeT[k][f] = W_e[(size_t)f * ED + k];
    }
    if (threadIdx.x < C * F) {
        int c = threadIdx.x >> 7, f = threadIdx.x & (F - 1);
        ebs[threadIdx.x] = ebias[f * 2 + c];
    }
    __syncthreads();

    int lane = threadIdx.x & 63;
    int node = blockIdx.x * 4 + (threadIdx.x >> 6);
    if (node >= NN) return;
    int beg = offs[node], end = offs[node + 1];
    float* orow = out + (size_t)node * (C * F);
    if (beg == end) {
        orow[lane] = 0.f; orow[64 + lane] = 0.f;
        orow[128 + lane] = 0.f; orow[192 + lane] = 0.f;
        return;
    }
    const float2* lg2 = reinterpret_cast<const float2*>(logits);
    float2* al2 = reinterpret_cast<float2*>(alpha_out);

    // max over segment
    float m0 = -3.402823466e38f, m1 = m0;
    for (int j = beg + lane; j < end; j += 64) {
        float2 lg = lg2[perm[j]];
        m0 = fmaxf(m0, lg.x); m1 = fmaxf(m1, lg.y);
    }
#pragma unroll
    for (int off = 32; off; off >>= 1) {
        m0 = fmaxf(m0, __shfl_xor(m0, off, 64));
        m1 = fmaxf(m1, __shfl_xor(m1, off, 64));
    }
    // sum of exp
    float s0 = 0.f, s1 = 0.f;
    for (int j = beg + lane; j < end; j += 64) {
        float2 lg = lg2[perm[j]];
        s0 += __expf(lg.x - m0); s1 += __expf(lg.y - m1);
    }
#pragma unroll
    for (int off = 32; off; off >>= 1) {
        s0 += __shfl_xor(s0, off, 64);
        s1 += __shfl_xor(s1, off, 64);
    }
    float inv0 = 1.f / (s0 + 1e-16f), inv1 = 1.f / (s1 + 1e-16f);

    // serial accumulation of h (ED dims) and g (F dims)
    float h0 = 0.f, h1 = 0.f;
    float g00 = 0.f, g01 = 0.f, g10 = 0.f, g11 = 0.f;
    for (int j = beg; j < end; ++j) {
        int e = __builtin_amdgcn_readfirstlane(perm[j]);
        float2 lg = lg2[e];
        float a0 = __expf(lg.x - m0) * inv0;
        float a1 = __expf(lg.y - m1) * inv1;
        if (lane == 0) { float2 av; av.x = a0; av.y = a1; al2[e] = av; }
        int src = __builtin_amdgcn_readfirstlane(ei[e]);
        float av = ea[(size_t)e * ED + lane];
        h0 = fmaf(a0, av, h0); h1 = fmaf(a1, av, h1);
        float xv0 = xb[(size_t)src * F + lane];
        float xv1 = xb[(size_t)src * F + 64 + lane];
        g00 = fmaf(a0, xv0, g00); g01 = fmaf(a1, xv0, g01);
        g10 = fmaf(a0, xv1, g10); g11 = fmaf(a1, xv1, g11);
    }
    // matvec W_e · h  (h lives distributed: dim k on lane k)
    float m00 = 0.f, m01 = 0.f, m10 = 0.f, m11 = 0.f;
    for (int k = 0; k < ED; ++k) {
        float hk0 = __shfl(h0, k, 64);
        float hk1 = __shfl(h1, k, 64);
        float w0 = WeT[k][lane], w1 = WeT[k][64 + lane];
        m00 = fmaf(hk0, w0, m00); m01 = fmaf(hk1, w0, m01);
        m10 = fmaf(hk0, w1, m10); m11 = fmaf(hk1, w1, m11);
    }
    float sa0 = s0 * inv0, sa1 = s1 * inv1;
    orow[lane]       = g00 + m00 + ebs[lane] * sa0;
    orow[64 + lane]  = g10 + m10 + ebs[64 + lane] * sa0;
    orow[128 + lane] = g01 + m01 + ebs[128 + lane] * sa1;
    orow[192 + lane] = g11 + m11 + ebs[192 + lane] * sa1;
}

extern "C" void kernel_launch(void* const* d_in, const int* in_sizes, int n_in,
                              void* d_out, int out_size, void* d_ws, size_t ws_size,
                              hipStream_t stream) {
    const float* x      = (const float*)d_in[0];
    const int*   ei     = (const int*)d_in[1];
    const float* ea     = (const float*)d_in[2];
    const float* W_l    = (const float*)d_in[3];
    const float* cb     = (const float*)d_in[4];
    const float* att    = (const float*)d_in[5];
    const float* att_sc = (const float*)d_in[6];
    const float* W_e    = (const float*)d_in[7];
    const float* ebias  = (const float*)d_in[8];

    float* out = (float*)d_out;
    float* alpha_out = out + (size_t)NN * C * F;

    float* ws = (float*)d_ws;
    float* xb     = ws;                    // 6.4M floats
    float* logits = ws + 6400000;          // 1.0M floats
    int* ibase  = (int*)(ws + 7400000);
    int* counts = ibase;                   // NN
    int* offs   = ibase + NN;              // NN+1
    int* cursor = ibase + 2 * NN + 1;      // NN
    int* perm   = ibase + 3 * NN + 1;      // NE

    hipMemsetAsync(counts, 0, NN * sizeof(int), stream);

    proj_mfma<<<782, 256, 0, stream>>>(x, W_l, xb);

    hist_kernel<<<(NE + 255) / 256, 256, 0, stream>>>(ei, counts);
    scan_kernel<<<1, 1024, 0, stream>>>(counts, offs, cursor);
    scatter_kernel<<<(NE + 255) / 256, 256, 0, stream>>>(ei, cursor, perm);

    edge_logits_mfma<<<2048, 256, 0, stream>>>(ei, ea, xb, W_e, cb, att,
                                               att_sc, ebias, logits);

    agg_factored<<<(NN + 3) / 4, 256, 0, stream>>>(ei, offs, perm, ea, xb, W_e,
                                                   ebias, logits, out, alpha_out);
}

// Round 4
// 529.181 us; speedup vs baseline: 2.7074x; 1.2370x over previous
//
#include <hip/hip_runtime.h>
#include <hip/hip_bf16.h>

#define NN 50000
#define NE 500000
#define F 128
#define K_IN 128
#define ED 64
#define C 2
#define NEG 0.2f

typedef __attribute__((ext_vector_type(8))) short short8;
typedef __attribute__((ext_vector_type(4))) float f32x4;

__device__ __forceinline__ short bf16r(float f) {
    unsigned u = __float_as_uint(f);
    unsigned r = (u + 0x7fffu + ((u >> 16) & 1u)) >> 16;
    return (short)r;
}

__device__ __forceinline__ short8 ldfrag(const float* base) {
    const float4* p = reinterpret_cast<const float4*>(base);
    float4 v0 = p[0], v1 = p[1];
    short8 r;
    r[0] = bf16r(v0.x); r[1] = bf16r(v0.y); r[2] = bf16r(v0.z); r[3] = bf16r(v0.w);
    r[4] = bf16r(v1.x); r[5] = bf16r(v1.y); r[6] = bf16r(v1.z); r[7] = bf16r(v1.w);
    return r;
}

// ---------------- projection via MFMA: xb = x @ W_l^T ----------------
__global__ __launch_bounds__(256) void proj_mfma(const float* __restrict__ x,
                                                 const float* __restrict__ W_l,
                                                 float* __restrict__ xb) {
    int lane = threadIdx.x & 63, wid = threadIdx.x >> 6;
    int grp = lane >> 4, col = lane & 15;
    int tile = blockIdx.x * 4 + wid;
    if (tile >= NN / 16) return;
    int n0 = tile * 16;

    f32x4 acc[8];
#pragma unroll
    for (int t = 0; t < 8; ++t) acc[t] = (f32x4){0.f, 0.f, 0.f, 0.f};

    const float* arow = x + (size_t)(n0 + col) * K_IN + grp * 8;
#pragma unroll
    for (int kt = 0; kt < 4; ++kt) {
        short8 a = ldfrag(arow + kt * 32);
#pragma unroll
        for (int t = 0; t < 8; ++t) {
            short8 b = ldfrag(W_l + (size_t)(t * 16 + col) * K_IN + kt * 32 + grp * 8);
            acc[t] = __builtin_amdgcn_mfma_f32_16x16x32_bf16(a, b, acc[t], 0, 0, 0);
        }
    }
#pragma unroll
    for (int j = 0; j < 4; ++j) {
        float* orow = xb + (size_t)(n0 + grp * 4 + j) * F + col;
#pragma unroll
        for (int t = 0; t < 8; ++t) orow[t * 16] = acc[t][j];
    }
}

// ---------------- CSR build ----------------
__global__ void hist_kernel(const int* __restrict__ ei, int* __restrict__ counts) {
    int e = blockIdx.x * blockDim.x + threadIdx.x;
    if (e < NE) atomicAdd(&counts[ei[NE + e]], 1);
}

__global__ __launch_bounds__(1024) void scan_kernel(const int* __restrict__ counts,
                                                    int* __restrict__ offs,
                                                    int* __restrict__ cursor) {
    __shared__ int wsum[16];
    __shared__ int carry_s;
    int lane = threadIdx.x & 63, w = threadIdx.x >> 6;
    if (threadIdx.x == 0) carry_s = 0;
    __syncthreads();
    for (int base = 0; base < NN; base += 1024) {
        int i = base + threadIdx.x;
        int v = (i < NN) ? counts[i] : 0;
        int xinc = v;
#pragma unroll
        for (int off = 1; off < 64; off <<= 1) {
            int y = __shfl_up(xinc, off, 64);
            if (lane >= off) xinc += y;
        }
        if (lane == 63) wsum[w] = xinc;
        __syncthreads();
        if (w == 0 && lane < 16) {
            int t = wsum[lane];
#pragma unroll
            for (int off = 1; off < 16; off <<= 1) {
                int y = __shfl_up(t, off, 16);
                if (lane >= off) t += y;
            }
            wsum[lane] = t;
        }
        __syncthreads();
        int woff = (w == 0) ? 0 : wsum[w - 1];
        int incl = carry_s + woff + xinc;
        int excl = incl - v;
        if (i < NN) { offs[i] = excl; cursor[i] = excl; }
        __syncthreads();
        if (threadIdx.x == 1023) carry_s = incl;
        __syncthreads();
    }
    if (threadIdx.x == 0) offs[NN] = carry_s;
}

__global__ void scatter_kernel(const int* __restrict__ ei, int* __restrict__ cursor,
                               int* __restrict__ perm) {
    int e = blockIdx.x * blockDim.x + threadIdx.x;
    if (e < NE) {
        int p = atomicAdd(&cursor[ei[NE + e]], 1);
        perm[p] = e;
    }
}

// ---------------- edge logits via MFMA emb ----------------
__global__ __launch_bounds__(256) void edge_logits_mfma(
    const int* __restrict__ ei, const float* __restrict__ ea,
    const float* __restrict__ xb, const float* __restrict__ W_e,
    const float* __restrict__ cb, const float* __restrict__ att,
    const float* __restrict__ att_sc, const float* __restrict__ ebias,
    float* __restrict__ logits) {
    int lane = threadIdx.x & 63, wid = threadIdx.x >> 6;
    int grp = lane >> 4, col = lane & 15;

    short8 B[8][2];
#pragma unroll
    for (int t = 0; t < 8; ++t)
#pragma unroll
        for (int kt = 0; kt < 2; ++kt)
            B[t][kt] = ldfrag(W_e + (size_t)(t * 16 + col) * ED + kt * 32 + grp * 8);

    float attv[8], cbe0[8], cbe1[8];
#pragma unroll
    for (int t = 0; t < 8; ++t) {
        int f = t * 16 + col;
        attv[t] = att[f];
        cbe0[t] = cb[f] + ebias[f * 2];
        cbe1[t] = cb[F + f] + ebias[f * 2 + 1];
    }
    float as0 = att_sc[0], as1 = att_sc[1];

    for (int tile = blockIdx.x * 4 + wid; tile < NE / 16; tile += gridDim.x * 4) {
        int e0 = tile * 16;
        // lane-parallel edge-index preload for the whole tile
        int e_lin = e0 + col;
        int srcv = ei[e_lin];
        int tgtv = ei[NE + e_lin];
        const float* arow = ea + (size_t)(e0 + col) * ED + grp * 8;
        short8 a0 = ldfrag(arow);
        short8 a1 = ldfrag(arow + 32);
        f32x4 acc[8];
#pragma unroll
        for (int t = 0; t < 8; ++t) acc[t] = (f32x4){0.f, 0.f, 0.f, 0.f};
#pragma unroll
        for (int t = 0; t < 8; ++t) {
            acc[t] = __builtin_amdgcn_mfma_f32_16x16x32_bf16(a0, B[t][0], acc[t], 0, 0, 0);
            acc[t] = __builtin_amdgcn_mfma_f32_16x16x32_bf16(a1, B[t][1], acc[t], 0, 0, 0);
        }
#pragma unroll
        for (int j = 0; j < 4; ++j) {
            int idx = grp * 4 + j;
            int src = __shfl(srcv, idx, 16);
            int tgt = __shfl(tgtv, idx, 16);
            int e = e0 + idx;
            const float* xbs = xb + (size_t)src * F + col;
            const float* xbt = xb + (size_t)tgt * F + col;
            float q0 = 0.f, q1 = 0.f;
#pragma unroll
            for (int t = 0; t < 8; ++t) {
                float s = xbs[t * 16] + xbt[t * 16] + acc[t][j];
                float u0 = s + cbe0[t]; u0 = fmaxf(u0, NEG * u0);
                float u1 = s + cbe1[t]; u1 = fmaxf(u1, NEG * u1);
                q0 = fmaf(u0, attv[t], q0);
                q1 = fmaf(u1, attv[t], q1);
            }
#pragma unroll
            for (int off = 8; off; off >>= 1) {
                q0 += __shfl_xor(q0, off, 16);
                q1 += __shfl_xor(q1, off, 16);
            }
            if (col == 0) {
                float2 o; o.x = q0 * as0; o.y = q1 * as1;
                *reinterpret_cast<float2*>(logits + 2 * (size_t)e) = o;
            }
        }
    }
}

// ---------------- factored CSR aggregation, lane-parallel preload ----------------
__global__ __launch_bounds__(256) void agg_factored(
    const int* __restrict__ ei, const int* __restrict__ offs,
    const int* __restrict__ perm, const float* __restrict__ ea,
    const float* __restrict__ xb, const float* __restrict__ W_e,
    const float* __restrict__ ebias, const float* __restrict__ logits,
    float* __restrict__ out, float* __restrict__ alpha_out) {
    __shared__ float WeT[ED][F];
    __shared__ float ebs[C * F];
    for (int i = threadIdx.x; i < ED * F; i += 256) {
        int f = i & (F - 1), k = i >> 7;
        WeT[k][f] = W_e[(size_t)f * ED + k];
    }
    if (threadIdx.x < C * F) {
        int c = threadIdx.x >> 7, f = threadIdx.x & (F - 1);
        ebs[threadIdx.x] = ebias[f * 2 + c];
    }
    __syncthreads();

    int lane = threadIdx.x & 63;
    int node = blockIdx.x * 4 + (threadIdx.x >> 6);
    if (node >= NN) return;
    int beg = offs[node], end = offs[node + 1];
    int deg = end - beg;
    float* orow = out + (size_t)node * (C * F);
    if (deg == 0) {
        orow[lane] = 0.f; orow[64 + lane] = 0.f;
        orow[128 + lane] = 0.f; orow[192 + lane] = 0.f;
        return;
    }
    const float2* lg2 = reinterpret_cast<const float2*>(logits);
    float2* al2 = reinterpret_cast<float2*>(alpha_out);

    float s0, s1, inv0, inv1;
    float h0 = 0.f, h1 = 0.f;
    float g00 = 0.f, g01 = 0.f, g10 = 0.f, g11 = 0.f;

    if (deg <= 64) {
        // ---------- fast path: whole segment resident in wave registers ----------
        bool act = lane < deg;
        int j = beg + (act ? lane : 0);
        int el = perm[j];
        int sl = ei[el];
        float2 lgl = lg2[el];
        float l0 = act ? lgl.x : -3.402823466e38f;
        float l1 = act ? lgl.y : -3.402823466e38f;
        float m0 = l0, m1 = l1;
#pragma unroll
        for (int off = 32; off; off >>= 1) {
            m0 = fmaxf(m0, __shfl_xor(m0, off, 64));
            m1 = fmaxf(m1, __shfl_xor(m1, off, 64));
        }
        float e0v = act ? __expf(l0 - m0) : 0.f;
        float e1v = act ? __expf(l1 - m1) : 0.f;
        s0 = e0v; s1 = e1v;
#pragma unroll
        for (int off = 32; off; off >>= 1) {
            s0 += __shfl_xor(s0, off, 64);
            s1 += __shfl_xor(s1, off, 64);
        }
        inv0 = 1.f / (s0 + 1e-16f); inv1 = 1.f / (s1 + 1e-16f);
        if (act) { float2 av; av.x = e0v * inv0; av.y = e1v * inv1; al2[el] = av; }
        // aggregation: e, src, alpha all from registers via readlane
#pragma unroll 4
        for (int jj = 0; jj < deg; ++jj) {
            int e = __shfl(el, jj, 64);
            int src = __shfl(sl, jj, 64);
            float a0 = __shfl(e0v, jj, 64) * inv0;
            float a1 = __shfl(e1v, jj, 64) * inv1;
            float av = ea[(size_t)e * ED + lane];
            h0 = fmaf(a0, av, h0); h1 = fmaf(a1, av, h1);
            float xv0 = xb[(size_t)src * F + lane];
            float xv1 = xb[(size_t)src * F + 64 + lane];
            g00 = fmaf(a0, xv0, g00); g01 = fmaf(a1, xv0, g01);
            g10 = fmaf(a0, xv1, g10); g11 = fmaf(a1, xv1, g11);
        }
    } else {
        // ---------- generic path (rare) ----------
        float m0 = -3.402823466e38f, m1 = m0;
        for (int j = beg + lane; j < end; j += 64) {
            float2 lg = lg2[perm[j]];
            m0 = fmaxf(m0, lg.x); m1 = fmaxf(m1, lg.y);
        }
#pragma unroll
        for (int off = 32; off; off >>= 1) {
            m0 = fmaxf(m0, __shfl_xor(m0, off, 64));
            m1 = fmaxf(m1, __shfl_xor(m1, off, 64));
        }
        s0 = 0.f; s1 = 0.f;
        for (int j = beg + lane; j < end; j += 64) {
            float2 lg = lg2[perm[j]];
            s0 += __expf(lg.x - m0); s1 += __expf(lg.y - m1);
        }
#pragma unroll
        for (int off = 32; off; off >>= 1) {
            s0 += __shfl_xor(s0, off, 64);
            s1 += __shfl_xor(s1, off, 64);
        }
        inv0 = 1.f / (s0 + 1e-16f); inv1 = 1.f / (s1 + 1e-16f);
        for (int j = beg + lane; j < end; j += 64) {
            int e = perm[j];
            float2 lg = lg2[e];
            float2 av; av.x = __expf(lg.x - m0) * inv0; av.y = __expf(lg.y - m1) * inv1;
            al2[e] = av;
        }
        for (int j = beg; j < end; ++j) {
            int e = __builtin_amdgcn_readfirstlane(perm[j]);
            float2 lg = lg2[e];
            float a0 = __expf(lg.x - m0) * inv0;
            float a1 = __expf(lg.y - m1) * inv1;
            int src = __builtin_amdgcn_readfirstlane(ei[e]);
            float av = ea[(size_t)e * ED + lane];
            h0 = fmaf(a0, av, h0); h1 = fmaf(a1, av, h1);
            float xv0 = xb[(size_t)src * F + lane];
            float xv1 = xb[(size_t)src * F + 64 + lane];
            g00 = fmaf(a0, xv0, g00); g01 = fmaf(a1, xv0, g01);
            g10 = fmaf(a0, xv1, g10); g11 = fmaf(a1, xv1, g11);
        }
    }
    // matvec W_e · h  (h distributed over lanes: dim k on lane k)
    float m00 = 0.f, m01 = 0.f, m10 = 0.f, m11 = 0.f;
    for (int k = 0; k < ED; ++k) {
        float hk0 = __shfl(h0, k, 64);
        float hk1 = __shfl(h1, k, 64);
        float w0 = WeT[k][lane], w1 = WeT[k][64 + lane];
        m00 = fmaf(hk0, w0, m00); m01 = fmaf(hk1, w0, m01);
        m10 = fmaf(hk0, w1, m10); m11 = fmaf(hk1, w1, m11);
    }
    float sa0 = s0 * inv0, sa1 = s1 * inv1;
    orow[lane]       = g00 + m00 + ebs[lane] * sa0;
    orow[64 + lane]  = g10 + m10 + ebs[64 + lane] * sa0;
    orow[128 + lane] = g01 + m01 + ebs[128 + lane] * sa1;
    orow[192 + lane] = g11 + m11 + ebs[192 + lane] * sa1;
}

extern "C" void kernel_launch(void* const* d_in, const int* in_sizes, int n_in,
                              void* d_out, int out_size, void* d_ws, size_t ws_size,
                              hipStream_t stream) {
    const float* x      = (const float*)d_in[0];
    const int*   ei     = (const int*)d_in[1];
    const float* ea     = (const float*)d_in[2];
    const float* W_l    = (const float*)d_in[3];
    const float* cb     = (const float*)d_in[4];
    const float* att    = (const float*)d_in[5];
    const float* att_sc = (const float*)d_in[6];
    const float* W_e    = (const float*)d_in[7];
    const float* ebias  = (const float*)d_in[8];

    float* out = (float*)d_out;
    float* alpha_out = out + (size_t)NN * C * F;

    float* ws = (float*)d_ws;
    float* xb     = ws;                    // 6.4M floats
    float* logits = ws + 6400000;          // 1.0M floats
    int* ibase  = (int*)(ws + 7400000);
    int* counts = ibase;                   // NN
    int* offs   = ibase + NN;              // NN+1
    int* cursor = ibase + 2 * NN + 1;      // NN
    int* perm   = ibase + 3 * NN + 1;      // NE

    hipMemsetAsync(counts, 0, NN * sizeof(int), stream);

    proj_mfma<<<782, 256, 0, stream>>>(x, W_l, xb);

    hist_kernel<<<(NE + 255) / 256, 256, 0, stream>>>(ei, counts);
    scan_kernel<<<1, 1024, 0, stream>>>(counts, offs, cursor);
    scatter_kernel<<<(NE + 255) / 256, 256, 0, stream>>>(ei, cursor, perm);

    edge_logits_mfma<<<2048, 256, 0, stream>>>(ei, ea, xb, W_e, cb, att,
                                               att_sc, ebias, logits);

    agg_factored<<<(NN + 3) / 4, 256, 0, stream>>>(ei, offs, perm, ea, xb, W_e,
                                                   ebias, logits, out, alpha_out);
}

// Round 5
// 415.280 us; speedup vs baseline: 3.4500x; 1.2743x over previous
//
#include <hip/hip_runtime.h>
#include <hip/hip_bf16.h>

#define NN 50000
#define NE 500000
#define F 128
#define K_IN 128
#define ED 64
#define C 2
#define NEG 0.2f
#define FLTMAX 3.402823466e38f

typedef __attribute__((ext_vector_type(8))) short short8;
typedef __attribute__((ext_vector_type(4))) float f32x4;

#define FMA4(acc, v, s) do { \
    acc[0] = fmaf((v)[0], (s), acc[0]); \
    acc[1] = fmaf((v)[1], (s), acc[1]); \
    acc[2] = fmaf((v)[2], (s), acc[2]); \
    acc[3] = fmaf((v)[3], (s), acc[3]); } while (0)

__device__ __forceinline__ short bf16r(float f) {
    unsigned u = __float_as_uint(f);
    unsigned r = (u + 0x7fffu + ((u >> 16) & 1u)) >> 16;
    return (short)r;
}

__device__ __forceinline__ short8 ldfrag(const float* base) {
    const float4* p = reinterpret_cast<const float4*>(base);
    float4 v0 = p[0], v1 = p[1];
    short8 r;
    r[0] = bf16r(v0.x); r[1] = bf16r(v0.y); r[2] = bf16r(v0.z); r[3] = bf16r(v0.w);
    r[4] = bf16r(v1.x); r[5] = bf16r(v1.y); r[6] = bf16r(v1.z); r[7] = bf16r(v1.w);
    return r;
}

// ---------------- projection via MFMA: xb = x @ W_l^T ----------------
__global__ __launch_bounds__(256) void proj_mfma(const float* __restrict__ x,
                                                 const float* __restrict__ W_l,
                                                 float* __restrict__ xb) {
    int lane = threadIdx.x & 63, wid = threadIdx.x >> 6;
    int grp = lane >> 4, col = lane & 15;
    int tile = blockIdx.x * 4 + wid;
    if (tile >= NN / 16) return;
    int n0 = tile * 16;

    f32x4 acc[8];
#pragma unroll
    for (int t = 0; t < 8; ++t) acc[t] = (f32x4){0.f, 0.f, 0.f, 0.f};

    const float* arow = x + (size_t)(n0 + col) * K_IN + grp * 8;
#pragma unroll
    for (int kt = 0; kt < 4; ++kt) {
        short8 a = ldfrag(arow + kt * 32);
#pragma unroll
        for (int t = 0; t < 8; ++t) {
            short8 b = ldfrag(W_l + (size_t)(t * 16 + col) * K_IN + kt * 32 + grp * 8);
            acc[t] = __builtin_amdgcn_mfma_f32_16x16x32_bf16(a, b, acc[t], 0, 0, 0);
        }
    }
#pragma unroll
    for (int j = 0; j < 4; ++j) {
        float* orow = xb + (size_t)(n0 + grp * 4 + j) * F + col;
#pragma unroll
        for (int t = 0; t < 8; ++t) orow[t * 16] = acc[t][j];
    }
}

// ---------------- CSR build ----------------
__global__ void hist_kernel(const int* __restrict__ ei, int* __restrict__ counts) {
    int e = blockIdx.x * blockDim.x + threadIdx.x;
    if (e < NE) atomicAdd(&counts[ei[NE + e]], 1);
}

__global__ __launch_bounds__(1024) void scan_kernel(const int* __restrict__ counts,
                                                    int* __restrict__ offs,
                                                    int* __restrict__ cursor) {
    __shared__ int wsum[16];
    __shared__ int carry_s;
    int lane = threadIdx.x & 63, w = threadIdx.x >> 6;
    if (threadIdx.x == 0) carry_s = 0;
    __syncthreads();
    for (int base = 0; base < NN; base += 1024) {
        int i = base + threadIdx.x;
        int v = (i < NN) ? counts[i] : 0;
        int xinc = v;
#pragma unroll
        for (int off = 1; off < 64; off <<= 1) {
            int y = __shfl_up(xinc, off, 64);
            if (lane >= off) xinc += y;
        }
        if (lane == 63) wsum[w] = xinc;
        __syncthreads();
        if (w == 0 && lane < 16) {
            int t = wsum[lane];
#pragma unroll
            for (int off = 1; off < 16; off <<= 1) {
                int y = __shfl_up(t, off, 16);
                if (lane >= off) t += y;
            }
            wsum[lane] = t;
        }
        __syncthreads();
        int woff = (w == 0) ? 0 : wsum[w - 1];
        int incl = carry_s + woff + xinc;
        int excl = incl - v;
        if (i < NN) { offs[i] = excl; cursor[i] = excl; }
        __syncthreads();
        if (threadIdx.x == 1023) carry_s = incl;
        __syncthreads();
    }
    if (threadIdx.x == 0) offs[NN] = carry_s;
}

// perm2[p] = {edge, src}
__global__ void scatter_kernel(const int* __restrict__ ei, int* __restrict__ cursor,
                               int2* __restrict__ perm2) {
    int e = blockIdx.x * blockDim.x + threadIdx.x;
    if (e < NE) {
        int src = ei[e];
        int p = atomicAdd(&cursor[ei[NE + e]], 1);
        int2 v; v.x = e; v.y = src;
        perm2[p] = v;
    }
}

// ---------------- edge logits over SORTED positions ----------------
__global__ __launch_bounds__(256) void edge_logits_mfma(
    const int* __restrict__ ei, const int2* __restrict__ perm2,
    const float* __restrict__ ea,
    const float* __restrict__ xb, const float* __restrict__ W_e,
    const float* __restrict__ cb, const float* __restrict__ att,
    const float* __restrict__ att_sc, const float* __restrict__ ebias,
    float* __restrict__ lgs) {
    int lane = threadIdx.x & 63, wid = threadIdx.x >> 6;
    int grp = lane >> 4, col = lane & 15;

    short8 B[8][2];
#pragma unroll
    for (int t = 0; t < 8; ++t)
#pragma unroll
        for (int kt = 0; kt < 2; ++kt)
            B[t][kt] = ldfrag(W_e + (size_t)(t * 16 + col) * ED + kt * 32 + grp * 8);

    float attv[8], cbe0[8], cbe1[8];
#pragma unroll
    for (int t = 0; t < 8; ++t) {
        int f = t * 16 + col;
        attv[t] = att[f];
        cbe0[t] = cb[f] + ebias[f * 2];
        cbe1[t] = cb[F + f] + ebias[f * 2 + 1];
    }
    float as0 = att_sc[0], as1 = att_sc[1];
    float2* lgs2 = reinterpret_cast<float2*>(lgs);

    for (int tile = blockIdx.x * 4 + wid; tile < NE / 16; tile += gridDim.x * 4) {
        int p0 = tile * 16;
        int2 pe = perm2[p0 + col];
        int eperm = pe.x;
        int srcv = pe.y;
        int tgtv = ei[NE + eperm];
        const float* arow = ea + (size_t)eperm * ED + grp * 8;
        short8 a0 = ldfrag(arow);
        short8 a1 = ldfrag(arow + 32);
        f32x4 acc[8];
#pragma unroll
        for (int t = 0; t < 8; ++t) acc[t] = (f32x4){0.f, 0.f, 0.f, 0.f};
#pragma unroll
        for (int t = 0; t < 8; ++t) {
            acc[t] = __builtin_amdgcn_mfma_f32_16x16x32_bf16(a0, B[t][0], acc[t], 0, 0, 0);
            acc[t] = __builtin_amdgcn_mfma_f32_16x16x32_bf16(a1, B[t][1], acc[t], 0, 0, 0);
        }
#pragma unroll
        for (int j = 0; j < 4; ++j) {
            int idx = grp * 4 + j;
            int src = __shfl(srcv, idx, 16);
            int tgt = __shfl(tgtv, idx, 16);
            const float* xbs = xb + (size_t)src * F + col;
            const float* xbt = xb + (size_t)tgt * F + col;
            float q0 = 0.f, q1 = 0.f;
#pragma unroll
            for (int t = 0; t < 8; ++t) {
                float s = xbs[t * 16] + xbt[t * 16] + acc[t][j];
                float u0 = s + cbe0[t]; u0 = fmaxf(u0, NEG * u0);
                float u1 = s + cbe1[t]; u1 = fmaxf(u1, NEG * u1);
                q0 = fmaf(u0, attv[t], q0);
                q1 = fmaf(u1, attv[t], q1);
            }
#pragma unroll
            for (int off = 8; off; off >>= 1) {
                q0 += __shfl_xor(q0, off, 16);
                q1 += __shfl_xor(q1, off, 16);
            }
            if (col == 0) {
                float2 o; o.x = q0 * as0; o.y = q1 * as1;
                lgs2[p0 + idx] = o;
            }
        }
    }
}

// gather 4 edges/iter into float4 accumulators
__device__ __forceinline__ void gather4(int cdeg, int el, int sl, float e0v, float e1v,
                                        float inv0, float inv1,
                                        const float* __restrict__ ea,
                                        const float* __restrict__ xb, int lane,
                                        f32x4& h0q, f32x4& h1q, f32x4& g0, f32x4& g1) {
    int quad = lane >> 4, sub16 = lane & 15;
    int half = lane >> 5, sub32 = lane & 31;
    for (int jj = 0; jj < cdeg; jj += 4) {
        int idx = jj + quad;
        int cidx = min(idx, cdeg - 1);
        float w0 = (idx < cdeg) ? inv0 : 0.f;
        float w1 = (idx < cdeg) ? inv1 : 0.f;
        float a0q = __shfl(e0v, cidx, 64) * w0;
        float a1q = __shfl(e1v, cidx, 64) * w1;
        int eq = __shfl(el, cidx, 64);
        f32x4 ev = *reinterpret_cast<const f32x4*>(ea + (size_t)eq * ED + sub16 * 4);
        FMA4(h0q, ev, a0q); FMA4(h1q, ev, a1q);

        int idh = jj + half;
        int ch = min(idh, cdeg - 1);
        float b0 = (idh < cdeg) ? inv0 : 0.f;
        float b1 = (idh < cdeg) ? inv1 : 0.f;
        float aA0 = __shfl(e0v, ch, 64) * b0;
        float aA1 = __shfl(e1v, ch, 64) * b1;
        int sA = __shfl(sl, ch, 64);
        f32x4 xv = *reinterpret_cast<const f32x4*>(xb + (size_t)sA * F + sub32 * 4);
        FMA4(g0, xv, aA0); FMA4(g1, xv, aA1);

        int idh2 = jj + 2 + half;
        int ch2 = min(idh2, cdeg - 1);
        float c0 = (idh2 < cdeg) ? inv0 : 0.f;
        float c1 = (idh2 < cdeg) ? inv1 : 0.f;
        float aB0 = __shfl(e0v, ch2, 64) * c0;
        float aB1 = __shfl(e1v, ch2, 64) * c1;
        int sB = __shfl(sl, ch2, 64);
        f32x4 xv2 = *reinterpret_cast<const f32x4*>(xb + (size_t)sB * F + sub32 * 4);
        FMA4(g0, xv2, aB0); FMA4(g1, xv2, aB1);
    }
}

// ---------------- factored CSR aggregation, float4 domain ----------------
__global__ __launch_bounds__(512) void agg_fast(
    const int* __restrict__ offs, const int2* __restrict__ perm2,
    const float* __restrict__ ea, const float* __restrict__ xb,
    const float* __restrict__ W_e, const float* __restrict__ ebias,
    const float* __restrict__ lgs,
    float* __restrict__ out, float* __restrict__ alpha_out) {
    __shared__ float WeT[ED][F]; // WeT[k][f] = W_e[f][k]
    for (int i = threadIdx.x; i < ED * F; i += 512) {
        int f = i & (F - 1), k = i >> 7;
        WeT[k][f] = W_e[(size_t)f * ED + k];
    }
    __syncthreads();

    int lane = threadIdx.x & 63;
    int node = blockIdx.x * 8 + (threadIdx.x >> 6);
    if (node >= NN) return;
    int beg = offs[node], end = offs[node + 1];
    int deg = end - beg;
    int half = lane >> 5, sub32 = lane & 31;
    float* orow = out + (size_t)node * (C * F);

    if (deg == 0) {
        f32x4 z = (f32x4){0.f, 0.f, 0.f, 0.f};
        *reinterpret_cast<f32x4*>(orow + half * F + sub32 * 4) = z;
        return;
    }
    const float2* lgs2 = reinterpret_cast<const float2*>(lgs);
    float2* al2 = reinterpret_cast<float2*>(alpha_out);

    f32x4 h0q = (f32x4){0.f,0.f,0.f,0.f}, h1q = h0q, gA0 = h0q, gA1 = h0q;
    float s0, s1, inv0, inv1;

    if (deg <= 64) {
        int jl = beg + min(lane, deg - 1);
        int2 pe = perm2[jl];
        int el = pe.x, sl = pe.y;
        float2 lgl = lgs2[jl];
        bool act = lane < deg;
        float l0 = act ? lgl.x : -FLTMAX;
        float l1 = act ? lgl.y : -FLTMAX;
        float m0 = l0, m1 = l1;
#pragma unroll
        for (int off = 32; off; off >>= 1) {
            m0 = fmaxf(m0, __shfl_xor(m0, off, 64));
            m1 = fmaxf(m1, __shfl_xor(m1, off, 64));
        }
        float e0v = act ? __expf(l0 - m0) : 0.f;
        float e1v = act ? __expf(l1 - m1) : 0.f;
        s0 = e0v; s1 = e1v;
#pragma unroll
        for (int off = 32; off; off >>= 1) {
            s0 += __shfl_xor(s0, off, 64);
            s1 += __shfl_xor(s1, off, 64);
        }
        inv0 = 1.f / (s0 + 1e-16f); inv1 = 1.f / (s1 + 1e-16f);
        if (act) { float2 av; av.x = e0v * inv0; av.y = e1v * inv1; al2[el] = av; }
        gather4(deg, el, sl, e0v, e1v, inv0, inv1, ea, xb, lane, h0q, h1q, gA0, gA1);
    } else {
        // generic: two strided passes for m and s, then 64-edge chunks
        float m0 = -FLTMAX, m1 = -FLTMAX;
        for (int j = beg + lane; j < end; j += 64) {
            float2 lg = lgs2[j];
            m0 = fmaxf(m0, lg.x); m1 = fmaxf(m1, lg.y);
        }
#pragma unroll
        for (int off = 32; off; off >>= 1) {
            m0 = fmaxf(m0, __shfl_xor(m0, off, 64));
            m1 = fmaxf(m1, __shfl_xor(m1, off, 64));
        }
        s0 = 0.f; s1 = 0.f;
        for (int j = beg + lane; j < end; j += 64) {
            float2 lg = lgs2[j];
            s0 += __expf(lg.x - m0); s1 += __expf(lg.y - m1);
        }
#pragma unroll
        for (int off = 32; off; off >>= 1) {
            s0 += __shfl_xor(s0, off, 64);
            s1 += __shfl_xor(s1, off, 64);
        }
        inv0 = 1.f / (s0 + 1e-16f); inv1 = 1.f / (s1 + 1e-16f);
        for (int cb0 = beg; cb0 < end; cb0 += 64) {
            int cdeg = min(64, end - cb0);
            int jl = cb0 + min(lane, cdeg - 1);
            int2 pe = perm2[jl];
            int el = pe.x, sl = pe.y;
            float2 lgl = lgs2[jl];
            bool act = lane < cdeg;
            float e0v = act ? __expf(lgl.x - m0) : 0.f;
            float e1v = act ? __expf(lgl.y - m1) : 0.f;
            if (act) { float2 av; av.x = e0v * inv0; av.y = e1v * inv1; al2[el] = av; }
            gather4(cdeg, el, sl, e0v, e1v, inv0, inv1, ea, xb, lane, h0q, h1q, gA0, gA1);
        }
    }

    // reduce h across quads, g across halves
#pragma unroll
    for (int ccc = 0; ccc < 4; ++ccc) {
        h0q[ccc] += __shfl_xor(h0q[ccc], 16, 64);
        h0q[ccc] += __shfl_xor(h0q[ccc], 32, 64);
        h1q[ccc] += __shfl_xor(h1q[ccc], 16, 64);
        h1q[ccc] += __shfl_xor(h1q[ccc], 32, 64);
        gA0[ccc] += __shfl_xor(gA0[ccc], 32, 64);
        gA1[ccc] += __shfl_xor(gA1[ccc], 32, 64);
    }
    // channel-packed h for bpermute: lanes<32 carry ch0, lanes>=32 carry ch1
    f32x4 hpack = half ? h1q : h0q;
    // matvec m4[f4] = sum_k h[k] * WeT[k][f4] for this lane's channel
    f32x4 m4 = (f32x4){0.f, 0.f, 0.f, 0.f};
    int srcbase = (half << 5);
#pragma unroll 4
    for (int k4 = 0; k4 < 16; ++k4) {
#pragma unroll
        for (int cc = 0; cc < 4; ++cc) {
            int k = k4 * 4 + cc;
            float hk = __shfl(hpack[cc], srcbase + k4, 64);
            const f32x4 w = *reinterpret_cast<const f32x4*>(&WeT[k][sub32 * 4]);
            FMA4(m4, w, hk);
        }
    }
    f32x4 gsel = half ? gA1 : gA0;
    float sa = (half ? s1 * inv1 : s0 * inv0);
    f32x4 res;
#pragma unroll
    for (int cc = 0; cc < 4; ++cc) {
        float eb = ebias[(sub32 * 4 + cc) * 2 + half];
        res[cc] = gsel[cc] + m4[cc] + eb * sa;
    }
    *reinterpret_cast<f32x4*>(orow + half * F + sub32 * 4) = res;
}

extern "C" void kernel_launch(void* const* d_in, const int* in_sizes, int n_in,
                              void* d_out, int out_size, void* d_ws, size_t ws_size,
                              hipStream_t stream) {
    const float* x      = (const float*)d_in[0];
    const int*   ei     = (const int*)d_in[1];
    const float* ea     = (const float*)d_in[2];
    const float* W_l    = (const float*)d_in[3];
    const float* cb     = (const float*)d_in[4];
    const float* att    = (const float*)d_in[5];
    const float* att_sc = (const float*)d_in[6];
    const float* W_e    = (const float*)d_in[7];
    const float* ebias  = (const float*)d_in[8];

    float* out = (float*)d_out;
    float* alpha_out = out + (size_t)NN * C * F;

    float* ws = (float*)d_ws;
    float* xb   = ws;                      // 6,400,000 floats
    float* lgs  = ws + 6400000;            // 1,000,000 floats (sorted logits)
    int* ibase  = (int*)(ws + 7400000);
    int* counts = ibase;                   // NN (reused as cursor)
    int* offs   = ibase + NN;              // NN+2 (padded for alignment)
    int2* perm2 = (int2*)(ibase + 2 * NN + 2); // NE int2

    hipMemsetAsync(counts, 0, NN * sizeof(int), stream);

    proj_mfma<<<782, 256, 0, stream>>>(x, W_l, xb);

    hist_kernel<<<(NE + 255) / 256, 256, 0, stream>>>(ei, counts);
    scan_kernel<<<1, 1024, 0, stream>>>(counts, offs, counts); // cursor aliases counts
    scatter_kernel<<<(NE + 255) / 256, 256, 0, stream>>>(ei, counts, perm2);

    edge_logits_mfma<<<2048, 256, 0, stream>>>(ei, perm2, ea, xb, W_e, cb, att,
                                               att_sc, ebias, lgs);

    agg_fast<<<NN / 8, 512, 0, stream>>>(offs, perm2, ea, xb, W_e, ebias, lgs,
                                         out, alpha_out);
}

// Round 6
// 368.384 us; speedup vs baseline: 3.8892x; 1.1273x over previous
//
#include <hip/hip_runtime.h>
#include <hip/hip_bf16.h>

#define NN 50000
#define NE 500000
#define F 128
#define K_IN 128
#define ED 64
#define C 2
#define NEG 0.2f
#define FLTMAX 3.402823466e38f

typedef __attribute__((ext_vector_type(8))) short short8;
typedef __attribute__((ext_vector_type(4))) float f32x4;

#define FMA4(acc, v, s) do { \
    acc[0] = fmaf((v)[0], (s), acc[0]); \
    acc[1] = fmaf((v)[1], (s), acc[1]); \
    acc[2] = fmaf((v)[2], (s), acc[2]); \
    acc[3] = fmaf((v)[3], (s), acc[3]); } while (0)

__device__ __forceinline__ short bf16r(float f) {
    unsigned u = __float_as_uint(f);
    unsigned r = (u + 0x7fffu + ((u >> 16) & 1u)) >> 16;
    return (short)r;
}

__device__ __forceinline__ short8 ldfrag(const float* base) {
    const float4* p = reinterpret_cast<const float4*>(base);
    float4 v0 = p[0], v1 = p[1];
    short8 r;
    r[0] = bf16r(v0.x); r[1] = bf16r(v0.y); r[2] = bf16r(v0.z); r[3] = bf16r(v0.w);
    r[4] = bf16r(v1.x); r[5] = bf16r(v1.y); r[6] = bf16r(v1.z); r[7] = bf16r(v1.w);
    return r;
}

// ---------------- projection via MFMA: xb = x @ W_l^T ----------------
__global__ __launch_bounds__(256) void proj_mfma(const float* __restrict__ x,
                                                 const float* __restrict__ W_l,
                                                 float* __restrict__ xb) {
    int lane = threadIdx.x & 63, wid = threadIdx.x >> 6;
    int grp = lane >> 4, col = lane & 15;
    int tile = blockIdx.x * 4 + wid;
    if (tile >= NN / 16) return;
    int n0 = tile * 16;

    f32x4 acc[8];
#pragma unroll
    for (int t = 0; t < 8; ++t) acc[t] = (f32x4){0.f, 0.f, 0.f, 0.f};

    const float* arow = x + (size_t)(n0 + col) * K_IN + grp * 8;
#pragma unroll
    for (int kt = 0; kt < 4; ++kt) {
        short8 a = ldfrag(arow + kt * 32);
#pragma unroll
        for (int t = 0; t < 8; ++t) {
            short8 b = ldfrag(W_l + (size_t)(t * 16 + col) * K_IN + kt * 32 + grp * 8);
            acc[t] = __builtin_amdgcn_mfma_f32_16x16x32_bf16(a, b, acc[t], 0, 0, 0);
        }
    }
#pragma unroll
    for (int j = 0; j < 4; ++j) {
        float* orow = xb + (size_t)(n0 + grp * 4 + j) * F + col;
#pragma unroll
        for (int t = 0; t < 8; ++t) orow[t * 16] = acc[t][j];
    }
}

// ---------------- CSR build ----------------
__global__ void hist_kernel(const int* __restrict__ ei, int* __restrict__ counts) {
    int e = blockIdx.x * blockDim.x + threadIdx.x;
    if (e < NE) atomicAdd(&counts[ei[NE + e]], 1);
}

// hierarchical scan: scan1 (per-block), scan2 (block sums), scan3 (add + cursor)
__global__ __launch_bounds__(1024) void scan1_kernel(const int* __restrict__ counts,
                                                     int* __restrict__ offs,
                                                     int* __restrict__ bsum) {
    __shared__ int wsum[16];
    int i = blockIdx.x * 1024 + threadIdx.x;
    int lane = threadIdx.x & 63, w = threadIdx.x >> 6;
    int v = (i < NN) ? counts[i] : 0;
    int x = v;
#pragma unroll
    for (int off = 1; off < 64; off <<= 1) {
        int y = __shfl_up(x, off, 64);
        if (lane >= off) x += y;
    }
    if (lane == 63) wsum[w] = x;
    __syncthreads();
    if (w == 0 && lane < 16) {
        int t = wsum[lane];
#pragma unroll
        for (int off = 1; off < 16; off <<= 1) {
            int y = __shfl_up(t, off, 16);
            if (lane >= off) t += y;
        }
        wsum[lane] = t;
    }
    __syncthreads();
    int woff = (w == 0) ? 0 : wsum[w - 1];
    if (i < NN) offs[i] = woff + x - v;
    if (threadIdx.x == 1023) bsum[blockIdx.x] = woff + x;
}

__global__ void scan2_kernel(int* __restrict__ bsum, int nb) {
    int tid = threadIdx.x;
    int v = (tid < nb) ? bsum[tid] : 0;
    int x = v;
#pragma unroll
    for (int off = 1; off < 64; off <<= 1) {
        int y = __shfl_up(x, off, 64);
        if (tid >= off) x += y;
    }
    if (tid < nb) bsum[tid] = x - v;
}

__global__ __launch_bounds__(1024) void scan3_kernel(int* __restrict__ offs,
                                                     const int* __restrict__ bsum,
                                                     int* __restrict__ cursor) {
    int i = blockIdx.x * 1024 + threadIdx.x;
    if (i < NN) {
        int o = offs[i] + bsum[blockIdx.x];
        offs[i] = o;
        cursor[i] = o;
    }
    if (i == 0) offs[NN] = NE;
}

// perm2[p] = {edge, src}
__global__ void scatter_kernel(const int* __restrict__ ei, int* __restrict__ cursor,
                               int2* __restrict__ perm2) {
    int e = blockIdx.x * blockDim.x + threadIdx.x;
    if (e < NE) {
        int src = ei[e];
        int p = atomicAdd(&cursor[ei[NE + e]], 1);
        int2 v; v.x = e; v.y = src;
        perm2[p] = v;
    }
}

// ---------------- edge logits over SORTED positions ----------------
__global__ __launch_bounds__(256) void edge_logits_mfma(
    const int* __restrict__ ei, const int2* __restrict__ perm2,
    const float* __restrict__ ea,
    const float* __restrict__ xb, const float* __restrict__ W_e,
    const float* __restrict__ cb, const float* __restrict__ att,
    const float* __restrict__ att_sc, const float* __restrict__ ebias,
    float* __restrict__ lgs) {
    int lane = threadIdx.x & 63, wid = threadIdx.x >> 6;
    int grp = lane >> 4, col = lane & 15;

    short8 B[8][2];
#pragma unroll
    for (int t = 0; t < 8; ++t)
#pragma unroll
        for (int kt = 0; kt < 2; ++kt)
            B[t][kt] = ldfrag(W_e + (size_t)(t * 16 + col) * ED + kt * 32 + grp * 8);

    float attv[8], cbe0[8], cbe1[8];
#pragma unroll
    for (int t = 0; t < 8; ++t) {
        int f = t * 16 + col;
        attv[t] = att[f];
        cbe0[t] = cb[f] + ebias[f * 2];
        cbe1[t] = cb[F + f] + ebias[f * 2 + 1];
    }
    float as0 = att_sc[0], as1 = att_sc[1];
    float2* lgs2 = reinterpret_cast<float2*>(lgs);

    for (int tile = blockIdx.x * 4 + wid; tile < NE / 16; tile += gridDim.x * 4) {
        int p0 = tile * 16;
        int2 pe = perm2[p0 + col];
        int eperm = pe.x;
        int srcv = pe.y;
        int tgtv = ei[NE + eperm];
        const float* arow = ea + (size_t)eperm * ED + grp * 8;
        short8 a0 = ldfrag(arow);
        short8 a1 = ldfrag(arow + 32);
        f32x4 acc[8];
#pragma unroll
        for (int t = 0; t < 8; ++t) acc[t] = (f32x4){0.f, 0.f, 0.f, 0.f};
#pragma unroll
        for (int t = 0; t < 8; ++t) {
            acc[t] = __builtin_amdgcn_mfma_f32_16x16x32_bf16(a0, B[t][0], acc[t], 0, 0, 0);
            acc[t] = __builtin_amdgcn_mfma_f32_16x16x32_bf16(a1, B[t][1], acc[t], 0, 0, 0);
        }
#pragma unroll
        for (int j = 0; j < 4; ++j) {
            int idx = grp * 4 + j;
            int src = __shfl(srcv, idx, 16);
            int tgt = __shfl(tgtv, idx, 16);
            const float* xbs = xb + (size_t)src * F + col;
            const float* xbt = xb + (size_t)tgt * F + col;
            float q0 = 0.f, q1 = 0.f;
#pragma unroll
            for (int t = 0; t < 8; ++t) {
                float s = xbs[t * 16] + xbt[t * 16] + acc[t][j];
                float u0 = s + cbe0[t]; u0 = fmaxf(u0, NEG * u0);
                float u1 = s + cbe1[t]; u1 = fmaxf(u1, NEG * u1);
                q0 = fmaf(u0, attv[t], q0);
                q1 = fmaf(u1, attv[t], q1);
            }
#pragma unroll
            for (int off = 8; off; off >>= 1) {
                q0 += __shfl_xor(q0, off, 16);
                q1 += __shfl_xor(q1, off, 16);
            }
            if (col == 0) {
                float2 o; o.x = q0 * as0; o.y = q1 * as1;
                lgs2[p0 + idx] = o;
            }
        }
    }
}

// gather 4 edges/iter into float4 accumulators
__device__ __forceinline__ void gather4(int cdeg, int el, int sl, float e0v, float e1v,
                                        float inv0, float inv1,
                                        const float* __restrict__ ea,
                                        const float* __restrict__ xb, int lane,
                                        f32x4& h0q, f32x4& h1q, f32x4& g0, f32x4& g1) {
    int quad = lane >> 4, sub16 = lane & 15;
    int half = lane >> 5, sub32 = lane & 31;
    for (int jj = 0; jj < cdeg; jj += 4) {
        int idx = jj + quad;
        int cidx = min(idx, cdeg - 1);
        float w0 = (idx < cdeg) ? inv0 : 0.f;
        float w1 = (idx < cdeg) ? inv1 : 0.f;
        float a0q = __shfl(e0v, cidx, 64) * w0;
        float a1q = __shfl(e1v, cidx, 64) * w1;
        int eq = __shfl(el, cidx, 64);
        f32x4 ev = *reinterpret_cast<const f32x4*>(ea + (size_t)eq * ED + sub16 * 4);
        FMA4(h0q, ev, a0q); FMA4(h1q, ev, a1q);

        int idh = jj + half;
        int ch = min(idh, cdeg - 1);
        float b0 = (idh < cdeg) ? inv0 : 0.f;
        float b1 = (idh < cdeg) ? inv1 : 0.f;
        float aA0 = __shfl(e0v, ch, 64) * b0;
        float aA1 = __shfl(e1v, ch, 64) * b1;
        int sA = __shfl(sl, ch, 64);
        f32x4 xv = *reinterpret_cast<const f32x4*>(xb + (size_t)sA * F + sub32 * 4);
        FMA4(g0, xv, aA0); FMA4(g1, xv, aA1);

        int idh2 = jj + 2 + half;
        int ch2 = min(idh2, cdeg - 1);
        float c0 = (idh2 < cdeg) ? inv0 : 0.f;
        float c1 = (idh2 < cdeg) ? inv1 : 0.f;
        float aB0 = __shfl(e0v, ch2, 64) * c0;
        float aB1 = __shfl(e1v, ch2, 64) * c1;
        int sB = __shfl(sl, ch2, 64);
        f32x4 xv2 = *reinterpret_cast<const f32x4*>(xb + (size_t)sB * F + sub32 * 4);
        FMA4(g0, xv2, aB0); FMA4(g1, xv2, aB1);
    }
}

// ---------------- factored CSR aggregation (no LDS, no matvec) ----------------
// writes: out = g + eb*sa  ;  H[node][c][64] = sum(alpha_c * ea)  ;  alpha
__global__ __launch_bounds__(512) void agg_fast(
    const int* __restrict__ offs, const int2* __restrict__ perm2,
    const float* __restrict__ ea, const float* __restrict__ xb,
    const float* __restrict__ ebias, const float* __restrict__ lgs,
    float* __restrict__ out, float* __restrict__ alpha_out,
    float* __restrict__ H) {
    int lane = threadIdx.x & 63;
    int node = blockIdx.x * 8 + (threadIdx.x >> 6);
    if (node >= NN) return;
    int beg = offs[node], end = offs[node + 1];
    int deg = end - beg;
    int half = lane >> 5, sub32 = lane & 31;
    float* orow = out + (size_t)node * (C * F);
    float* hrow = H + (size_t)node * (C * ED);

    if (deg == 0) {
        f32x4 z = (f32x4){0.f, 0.f, 0.f, 0.f};
        *reinterpret_cast<f32x4*>(orow + half * F + sub32 * 4) = z;
        if (lane < 32) *reinterpret_cast<f32x4*>(hrow + lane * 4) = z;
        return;
    }
    const float2* lgs2 = reinterpret_cast<const float2*>(lgs);
    float2* al2 = reinterpret_cast<float2*>(alpha_out);

    f32x4 h0q = (f32x4){0.f,0.f,0.f,0.f}, h1q = h0q, gA0 = h0q, gA1 = h0q;
    float s0, s1, inv0, inv1;

    if (deg <= 64) {
        int jl = beg + min(lane, deg - 1);
        int2 pe = perm2[jl];
        int el = pe.x, sl = pe.y;
        float2 lgl = lgs2[jl];
        bool act = lane < deg;
        float l0 = act ? lgl.x : -FLTMAX;
        float l1 = act ? lgl.y : -FLTMAX;
        float m0 = l0, m1 = l1;
#pragma unroll
        for (int off = 32; off; off >>= 1) {
            m0 = fmaxf(m0, __shfl_xor(m0, off, 64));
            m1 = fmaxf(m1, __shfl_xor(m1, off, 64));
        }
        float e0v = act ? __expf(l0 - m0) : 0.f;
        float e1v = act ? __expf(l1 - m1) : 0.f;
        s0 = e0v; s1 = e1v;
#pragma unroll
        for (int off = 32; off; off >>= 1) {
            s0 += __shfl_xor(s0, off, 64);
            s1 += __shfl_xor(s1, off, 64);
        }
        inv0 = 1.f / (s0 + 1e-16f); inv1 = 1.f / (s1 + 1e-16f);
        if (act) { float2 av; av.x = e0v * inv0; av.y = e1v * inv1; al2[el] = av; }
        gather4(deg, el, sl, e0v, e1v, inv0, inv1, ea, xb, lane, h0q, h1q, gA0, gA1);
    } else {
        float m0 = -FLTMAX, m1 = -FLTMAX;
        for (int j = beg + lane; j < end; j += 64) {
            float2 lg = lgs2[j];
            m0 = fmaxf(m0, lg.x); m1 = fmaxf(m1, lg.y);
        }
#pragma unroll
        for (int off = 32; off; off >>= 1) {
            m0 = fmaxf(m0, __shfl_xor(m0, off, 64));
            m1 = fmaxf(m1, __shfl_xor(m1, off, 64));
        }
        s0 = 0.f; s1 = 0.f;
        for (int j = beg + lane; j < end; j += 64) {
            float2 lg = lgs2[j];
            s0 += __expf(lg.x - m0); s1 += __expf(lg.y - m1);
        }
#pragma unroll
        for (int off = 32; off; off >>= 1) {
            s0 += __shfl_xor(s0, off, 64);
            s1 += __shfl_xor(s1, off, 64);
        }
        inv0 = 1.f / (s0 + 1e-16f); inv1 = 1.f / (s1 + 1e-16f);
        for (int cb0 = beg; cb0 < end; cb0 += 64) {
            int cdeg = min(64, end - cb0);
            int jl = cb0 + min(lane, cdeg - 1);
            int2 pe = perm2[jl];
            int el = pe.x, sl = pe.y;
            float2 lgl = lgs2[jl];
            bool act = lane < cdeg;
            float e0v = act ? __expf(lgl.x - m0) : 0.f;
            float e1v = act ? __expf(lgl.y - m1) : 0.f;
            if (act) { float2 av; av.x = e0v * inv0; av.y = e1v * inv1; al2[el] = av; }
            gather4(cdeg, el, sl, e0v, e1v, inv0, inv1, ea, xb, lane, h0q, h1q, gA0, gA1);
        }
    }

    // reduce h across quads, g across halves
#pragma unroll
    for (int ccc = 0; ccc < 4; ++ccc) {
        h0q[ccc] += __shfl_xor(h0q[ccc], 16, 64);
        h0q[ccc] += __shfl_xor(h0q[ccc], 32, 64);
        h1q[ccc] += __shfl_xor(h1q[ccc], 16, 64);
        h1q[ccc] += __shfl_xor(h1q[ccc], 32, 64);
        gA0[ccc] += __shfl_xor(gA0[ccc], 32, 64);
        gA1[ccc] += __shfl_xor(gA1[ccc], 32, 64);
    }
    // H row: lanes 0-15 -> channel 0, lanes 16-31 -> channel 1
    if (lane < 32) {
        f32x4 hv = (lane < 16) ? h0q : h1q;
        *reinterpret_cast<f32x4*>(hrow + ((lane >> 4) * ED) + (lane & 15) * 4) = hv;
    }
    f32x4 gsel = half ? gA1 : gA0;
    float sa = (half ? s1 * inv1 : s0 * inv0);
    f32x4 res;
#pragma unroll
    for (int cc = 0; cc < 4; ++cc) {
        float eb = ebias[(sub32 * 4 + cc) * 2 + half];
        res[cc] = gsel[cc] + eb * sa;
    }
    *reinterpret_cast<f32x4*>(orow + half * F + sub32 * 4) = res;
}

// ---------------- dense emb add: out[row][f] += sum_k H[row][k]*W_e[f][k] ----------------
// row = n*2 + c; out[row*128 + f]
__global__ __launch_bounds__(512) void emb_gemm(const float* __restrict__ H,
                                                const float* __restrict__ W_e,
                                                float* __restrict__ out) {
    __shared__ float WeT[ED][F];
    for (int i = threadIdx.x; i < ED * F; i += 512) {
        int f = i & (F - 1), k = i >> 7;
        WeT[k][f] = W_e[(size_t)f * ED + k];
    }
    __syncthreads();
    int lane = threadIdx.x & 63, wid = threadIdx.x >> 6;
    const int R = NN * C;
    for (int row = blockIdx.x * 8 + wid; row < R; row += gridDim.x * 8) {
        float h = H[(size_t)row * ED + lane];
        float m0 = 0.f, m1 = 0.f;
#pragma unroll
        for (int k = 0; k < ED; ++k) {
            float hk = __shfl(h, k, 64);
            m0 = fmaf(hk, WeT[k][lane], m0);
            m1 = fmaf(hk, WeT[k][lane + 64], m1);
        }
        float* op = out + (size_t)row * F;
        op[lane] += m0;
        op[lane + 64] += m1;
    }
}

extern "C" void kernel_launch(void* const* d_in, const int* in_sizes, int n_in,
                              void* d_out, int out_size, void* d_ws, size_t ws_size,
                              hipStream_t stream) {
    const float* x      = (const float*)d_in[0];
    const int*   ei     = (const int*)d_in[1];
    const float* ea     = (const float*)d_in[2];
    const float* W_l    = (const float*)d_in[3];
    const float* cb     = (const float*)d_in[4];
    const float* att    = (const float*)d_in[5];
    const float* att_sc = (const float*)d_in[6];
    const float* W_e    = (const float*)d_in[7];
    const float* ebias  = (const float*)d_in[8];

    float* out = (float*)d_out;
    float* alpha_out = out + (size_t)NN * C * F;

    float* ws = (float*)d_ws;
    float* xb   = ws;                          // 6,400,000 floats
    float* lgs  = ws + 6400000;                // 1,000,000 floats (sorted logits)
    int* ibase  = (int*)(ws + 7400000);
    int* counts = ibase;                       // NN (becomes cursor)
    int* offs   = ibase + NN;                  // NN+1
    int* bsum   = ibase + 2 * NN + 8;          // 64
    int2* perm2 = (int2*)(ibase + 2 * NN + 128); // NE int2
    float* H    = ws + 7400000 + (2 * NN + 128 + 2 * NE + 64) / 1; // after perm2
    // recompute cleanly: perm2 occupies ints [2NN+128, 2NN+128+2NE)
    H = (float*)(ibase + 2 * NN + 128 + 2 * NE);
    // align H to 16 bytes
    H = (float*)(((size_t)H + 15) & ~(size_t)15);

    hipMemsetAsync(counts, 0, NN * sizeof(int), stream);

    proj_mfma<<<782, 256, 0, stream>>>(x, W_l, xb);

    hist_kernel<<<(NE + 255) / 256, 256, 0, stream>>>(ei, counts);
    const int NB = (NN + 1023) / 1024; // 49
    scan1_kernel<<<NB, 1024, 0, stream>>>(counts, offs, bsum);
    scan2_kernel<<<1, 64, 0, stream>>>(bsum, NB);
    scan3_kernel<<<NB, 1024, 0, stream>>>(offs, bsum, counts); // counts = cursor
    scatter_kernel<<<(NE + 255) / 256, 256, 0, stream>>>(ei, counts, perm2);

    edge_logits_mfma<<<2048, 256, 0, stream>>>(ei, perm2, ea, xb, W_e, cb, att,
                                               att_sc, ebias, lgs);

    agg_fast<<<NN / 8, 512, 0, stream>>>(offs, perm2, ea, xb, ebias, lgs,
                                         out, alpha_out, H);

    emb_gemm<<<1024, 512, 0, stream>>>(H, W_e, out);
}